// Round 18
// baseline (62.134 us; speedup 1.0000x reference)
//
#include <hip/hip_runtime.h>
#include <cstdint>

#define BB 4
#define RR 512
#define CC 80
#define KK 100
#define NMS_TH 0.3f
#define SCORE_TH 0.1f
#define DWH_CLIP 4.135166556742356f

typedef unsigned short u16;
typedef unsigned int u32;
typedef unsigned long long u64;

__device__ __forceinline__ u32 f32_sortable(float f) {
  u32 u = __float_as_uint(f);
  u32 mask = (u32)((int)u >> 31) | 0x80000000u;
  return u ^ mask;
}
__device__ __forceinline__ float sortable_to_f32(u32 s) {
  u32 u = (s & 0x80000000u) ? (s ^ 0x80000000u) : ~s;
  return __uint_as_float(u);
}

// Kernel 1: one block of 512 per (b,c). Fused: score-sort (LDS-hybrid bitonic,
// double-buffered in aliased pool), decode, EAGER per-chunk row-masks (wave w
// owns chunk w; pure geometry, kept-independent), then lazy greedy NMS where
// chunk w's serial scan runs on wave w (rotation -> different SIMD per chunk
// and across lockstep co-resident blocks). ILP IoU loops with one __any per
// group + rare exact-divide fallback (validated R4-R17):
// q > TH <=> inter*(1+TH)/TH > ai+aj+1e-9 in reals; band +-2e-6 >> rounding
// error ~3e-7; exact IEEE-divide fallback for band cases.
__global__ __launch_bounds__(512) void nms_fused(
    const float* __restrict__ rois,     // [B,R,4]
    const float* __restrict__ scores,   // [B*R, C+1]
    const float* __restrict__ deltas,   // [B*R, (C+1)*4]
    const int*   __restrict__ im_hw,    // [B,2]
    u64*   __restrict__ cand_key,       // [B*C, K]
    float4* __restrict__ cand_box)      // [B*C, K]
{
#pragma clang fp contract(off)
  const int bc = blockIdx.x;
  const int b = bc / CC, c = bc % CC;
  const int tid = threadIdx.x;
  const int lane = tid & 63, wv = tid >> 6;

  __shared__ __align__(16) char pool[8192];  // keyarr | {rmk_w,kbox,ksc,karea}
  u64*    keyarr = (u64*)pool;               // [2*RR] during sort only
  u64*    rmk_w  = (u64*)pool;               // [8*64] after decode: chunk w rows
  float4* kbox   = (float4*)(pool + 4096);   // [KK]
  float*  ksc    = (float*)(pool + 5696);    // [KK]
  float*  karea  = (float*)(pool + 6096);    // [KK]
  __shared__ float4 box_s[RR];               // 8 KB sorted boxes
  __shared__ float  sco_s[RR];               // 2 KB sorted scores
  __shared__ u64    supacc_arr[8];
  __shared__ int    nkept_s;

  const float fh = (float)im_hw[b * 2 + 0] - 1.0f;
  const float fw = (float)im_hw[b * 2 + 1] - 1.0f;

  // ---- hybrid bitonic sort: shfl for j<64, double-buffered LDS for j>=64 ----
  {
    const float sc = scores[(b * RR + tid) * (CC + 1) + (c + 1)];
    u64 v = ((u64)(~f32_sortable(sc)) << 32) | (u32)tid;  // score desc, idx asc
    const u32 t = (u32)tid;
    u32 pp = 0;
    for (u32 kk = 2; kk <= RR; kk <<= 1) {
      for (u32 j = kk >> 1; j > 0; j >>= 1) {
        u64 p;
        if (j >= 64) {
          u64* buf = keyarr + (pp & 1) * RR;
          buf[t] = v;
          __syncthreads();
          p = buf[t ^ j];
          ++pp;
        } else {
          p = __shfl_xor(v, (int)j);
        }
        bool up = ((t & kk) == 0);
        bool lower = ((t & j) == 0);
        bool takemin = (up == lower);
        bool pless = (p < v);
        v = (takemin == pless) ? p : v;
      }
    }
    __syncthreads();               // all lanes done reading buf before final write
    keyarr[t] = v;
  }
  __syncthreads();

  // ---- decode into sorted order ----
  {
    const u64 kv = keyarr[tid];
    const int r = (int)(kv & 0xFFFFFFFFull);
    const float sc = sortable_to_f32(~(u32)(kv >> 32));   // bit-exact original
    const float4 roi = *(const float4*)&rois[(b * RR + r) * 4];
    const int base = (b * RR + r) * (CC + 1) + (c + 1);
    const float4 d = *(const float4*)&deltas[base * 4];

    float w  = roi.z - roi.x;
    float h  = roi.w - roi.y;
    float cx = roi.x + 0.5f * w;
    float cy = roi.y + 0.5f * h;
    float dw = fminf(d.z, DWH_CLIP);
    float dh = fminf(d.w, DWH_CLIP);
    float pcx = d.x * w + cx;
    float pcy = d.y * h + cy;
    float pw = w * expf(dw);
    float ph = h * expf(dh);
    float hx = 0.5f * pw, hy = 0.5f * ph;
    float x1 = fminf(fmaxf(pcx - hx, 0.0f), fw);
    float y1 = fminf(fmaxf(pcy - hy, 0.0f), fh);
    float x2 = fminf(fmaxf(pcx + hx, 0.0f), fw);
    float y2 = fminf(fmaxf(pcy + hy, 0.0f), fh);

    box_s[tid] = make_float4(x1, y1, x2, y2);
    sco_s[tid] = sc;
    if (tid == 0) nkept_s = 0;
  }
  __syncthreads();                  // keyarr dead; rmk_w/kbox/ksc/karea go live

  // ---- EAGER row-masks: wave wv computes chunk wv's full 64-col masks ----
  {
    const float4 bxr = box_s[wv * 64 + lane];
    const float ar = (bxr.z - bxr.x) * (bxr.w - bxr.y);
    const float areps = ar + 1e-9f;
    u64 myrow = 0;
    for (int g = 0; g < 8; ++g) {
      float4 cb[8]; float ca[8]; float inA[8];
      #pragma unroll
      for (int jj = 0; jj < 8; ++jj) {
        cb[jj] = box_s[wv * 64 + g * 8 + jj];             // broadcast
        ca[jj] = (cb[jj].z - cb[jj].x) * (cb[jj].w - cb[jj].y);
      }
      u64 grow = 0;
      u32 unca = 0;
      #pragma unroll
      for (int jj = 0; jj < 8; ++jj) {
        float iw = fminf(bxr.z, cb[jj].z) - fmaxf(bxr.x, cb[jj].x);
        float ih = fminf(bxr.w, cb[jj].w) - fmaxf(bxr.y, cb[jj].y);
        iw = fmaxf(iw, 0.0f);
        ih = fmaxf(ih, 0.0f);
        const float inter = iw * ih;
        inA[jj] = inter;
        const float S = ca[jj] + areps;
        const bool yes = inter * 4.3333247f > S;          // 13/3*(1-2e-6)
        const bool no  = inter * 4.3333420f < S;          // 13/3*(1+2e-6)
        grow |= yes ? (1ull << jj) : 0ull;
        unca |= (!(yes || no)) ? (1u << jj) : 0u;
      }
      if (__any(unca != 0)) {                             // ~never taken
        #pragma unroll
        for (int jj = 0; jj < 8; ++jj) {
          const float denom = ((ca[jj] + ar) - inA[jj]) + 1e-9f; // exact ref order
          const bool pe = inA[jj] / denom > NMS_TH;
          const u64 bit = 1ull << jj;
          if (unca & (1u << jj)) grow = pe ? (grow | bit) : (grow & ~bit);
        }
      }
      myrow |= grow << (g * 8);
    }
    myrow &= ~((2ull << lane) - 1ull);                    // only cols > row
    rmk_w[wv * 64 + lane] = myrow;
  }
  __syncthreads();

  // ---- lazy greedy NMS over 8 chunks of 64 ----
  int nk = 0;
  for (int w = 0; w < 8 && nk < KK; ++w) {
    const float4 bxc = box_s[w * 64 + lane];
    const float ar = (bxc.z - bxc.x) * (bxc.w - bxc.y);
    const float areps = ar + 1e-9f;

    // (b) suppression by previously-kept, wave-strided; no per-iter __any
    {
      bool sup = false, unca = false;
      for (int kx = wv; kx < nk; kx += 8) {
        const float4 kb = kbox[kx];                       // broadcast
        const float ka = karea[kx];
        float iw = fminf(bxc.z, kb.z) - fmaxf(bxc.x, kb.x);
        float ih = fminf(bxc.w, kb.w) - fmaxf(bxc.y, kb.y);
        iw = fmaxf(iw, 0.0f);
        ih = fmaxf(ih, 0.0f);
        const float inter = iw * ih;
        const float S = ka + areps;
        const bool yes = inter * 4.3333247f > S;
        const bool no  = inter * 4.3333420f < S;
        sup  = sup  || yes;
        unca = unca || (!(yes || no));
      }
      if (__any(unca && !sup)) {                          // ~never taken
        sup = false;
        for (int kx = wv; kx < nk; kx += 8) {             // exact re-run
          const float4 kb = kbox[kx];
          const float ka = karea[kx];
          float iw = fminf(bxc.z, kb.z) - fmaxf(bxc.x, kb.x);
          float ih = fminf(bxc.w, kb.w) - fmaxf(bxc.y, kb.y);
          iw = fmaxf(iw, 0.0f);
          ih = fmaxf(ih, 0.0f);
          const float inter = iw * ih;
          const float denom = ((ka + ar) - inter) + 1e-9f; // exact ref order
          sup = sup || (inter / denom > NMS_TH);
        }
      }
      const u64 bal = __ballot(sup);
      if (lane == 0) supacc_arr[wv] = bal;
    }
    __syncthreads();

    // (c) serial scan on wave w (rotation): ffs + readlane + and chain
    if (wv == w) {
      u64 sup2 = supacc_arr[0];
      #pragma unroll
      for (int ww = 1; ww < 8; ++ww) sup2 |= supacc_arr[ww];
      const u64 rm = rmk_w[w * 64 + lane];                // eager full row mask
      const u32 rlo = (u32)rm, rhi = (u32)(rm >> 32);
      u64 todo = __ballot(sco_s[w * 64 + lane] > SCORE_TH) & ~sup2;
      int nkl = nk;
      while (todo) {
        const int i = __ffsll((long long)todo) - 1;       // best remaining
        if (lane == 0) {
          const float4 kb = box_s[w * 64 + i];
          kbox[nkl] = kb;
          ksc[nkl] = sco_s[w * 64 + i];
          karea[nkl] = (kb.z - kb.x) * (kb.w - kb.y);
        }
        ++nkl;
        if (nkl >= KK) break;
        const u32 rl = (u32)__builtin_amdgcn_readlane((int)rlo, i);
        const u32 rh = (u32)__builtin_amdgcn_readlane((int)rhi, i);
        todo &= ~((2ull << i) - 1ull);                    // clear bits <= i
        todo &= ~(((u64)rh << 32) | rl);
      }
      if (lane == 0) nkept_s = nkl;
    }
    __syncthreads();
    nk = nkept_s;
  }

  // ---- emit candidates (pads unique, score = -1e9 = reference NEG) ----
  if (tid < KK) {
    const int kx = tid;
    u64 kv; float4 obx;
    if (kx < nk) {
      kv = ((u64)(~f32_sortable(ksc[kx])) << 32) | ((u64)(u32)c << 16) | (u32)kx;
      obx = kbox[kx];
    } else {
      kv = ((u64)(~f32_sortable(-1e9f)) << 32) | ((u64)(u32)c << 16) | (u32)kx;
      obx = make_float4(0.f, 0.f, 0.f, 0.f);
    }
    cand_key[bc * KK + kx] = kv;
    cand_box[bc * KK + kx] = obx;
  }
}

__device__ __forceinline__ void sort128(u64* smallkeys, int tid) {
  u64 v = (tid < 128) ? smallkeys[tid] : ~0ull;
  const u32 t = (u32)tid;
  for (u32 kk = 2; kk <= 128; kk <<= 1) {
    for (u32 j = kk >> 1; j > 0; j >>= 1) {
      if (j >= 64) {
        if (tid < 128) smallkeys[t] = v;
        __syncthreads();
        u64 p = (tid < 128) ? smallkeys[t ^ j] : ~0ull;
        __syncthreads();
        if (tid < 128) {
          bool up = ((t & kk) == 0);
          bool lower = ((t & j) == 0);
          bool takemin = (up == lower);
          bool pless = (p < v);
          v = (takemin == pless) ? p : v;
        }
      } else if (tid < 128) {
        u64 p = __shfl_xor(v, (int)j);
        bool up = ((t & kk) == 0);
        bool lower = ((t & j) == 0);
        bool takemin = (up == lower);
        bool pless = (p < v);
        v = (takemin == pless) ? p : v;
      }
    }
  }
  if (tid < 128) smallkeys[t] = v;
  __syncthreads();
}

// Kernel 2 (R15-proven): compaction-free register radix select per image.
__global__ __launch_bounds__(1024) void topk_select(
    const u64* __restrict__ cand_key,    // [B, C*K]
    const float4* __restrict__ cand_box, // [B*C, K]
    float* __restrict__ out)             // [B, K, 6]
{
  const int b = blockIdx.x;
  const int tid = threadIdx.x;
  const int lane = tid & 63, wv = tid >> 6;
  const int N = CC * KK;                 // 8000
  const u64* __restrict__ keys_g = cand_key + (size_t)b * N;

  __shared__ u32 whist[16][256];         // 16 KB
  __shared__ u32 bins[256];
  __shared__ u64 smallkeys[128];
  __shared__ int rank_s, q_s, ncand_s;
  __shared__ u32 cnt_s;

  u64 myk[8];
  #pragma unroll
  for (int i = 0; i < 8; ++i) {
    const int t = i * 1024 + tid;
    myk[i] = (t < N) ? keys_g[t] : ~0ull;
  }
  u32 mask8 = 0xFF;
  if (tid == 0) rank_s = KK - 1;

  int d = 7;
  int nc;
  for (;;) {
    for (int t = tid; t < 16 * 256; t += 1024) ((u32*)whist)[t] = 0;
    __syncthreads();
    const int sh = 8 * d;
    #pragma unroll
    for (int i = 0; i < 8; ++i) {
      if (mask8 & (1u << i)) {
        const u32 dig = (u32)((myk[i] >> sh) & 0xFF);
        atomicAdd(&whist[wv][dig], 1u);
      }
    }
    __syncthreads();
    if (tid < 256) {
      u32 s = 0;
      #pragma unroll
      for (int w = 0; w < 16; ++w) s += whist[w][tid];
      bins[tid] = s;
    }
    __syncthreads();
    if (wv == 0) {
      const u32 c0 = bins[lane * 4 + 0], c1 = bins[lane * 4 + 1];
      const u32 c2 = bins[lane * 4 + 2], c3 = bins[lane * 4 + 3];
      const u32 lsum = c0 + c1 + c2 + c3;
      u32 incl = lsum;
      #pragma unroll
      for (int off = 1; off < 64; off <<= 1) {
        const u32 v = __shfl_up(incl, off);
        if (lane >= off) incl += v;
      }
      const u32 excl = incl - lsum;
      const int rk = rank_s;
      const u32 s0 = excl, s1 = excl + c0, s2 = s1 + c1, s3 = s2 + c2;
      int q = -1; u32 nr = 0; u32 cnt = 0;
      if (rk >= (int)s0 && rk < (int)(s0 + c0)) { q = lane * 4 + 0; nr = rk - s0; cnt = c0; }
      else if (rk >= (int)s1 && rk < (int)(s1 + c1)) { q = lane * 4 + 1; nr = rk - s1; cnt = c1; }
      else if (rk >= (int)s2 && rk < (int)(s2 + c2)) { q = lane * 4 + 2; nr = rk - s2; cnt = c2; }
      else if (rk >= (int)s3 && rk < (int)(s3 + c3)) { q = lane * 4 + 3; nr = rk - s3; cnt = c3; }
      if (q >= 0) { q_s = q; rank_s = (int)nr; ncand_s = (int)cnt; }
    }
    __syncthreads();
    const u32 q = (u32)q_s;
    nc = ncand_s;
    #pragma unroll
    for (int i = 0; i < 8; ++i) {
      const u32 dig = (u32)((myk[i] >> sh) & 0xFF);
      if (dig != q) mask8 &= ~(1u << i);
    }
    if (nc <= 128 || d == 0) break;
    --d;
  }

  // gather the nc (<=128) candidates from registers
  if (tid == 0) cnt_s = 0;
  if (tid < 128) smallkeys[tid] = ~0ull;
  __syncthreads();
  #pragma unroll
  for (int i = 0; i < 8; ++i) {
    const bool m = (mask8 & (1u << i)) != 0;
    const u64 bal = __ballot(m);
    u32 base = 0;
    if (lane == 0 && bal) base = atomicAdd(&cnt_s, (u32)__popcll(bal));
    base = __shfl(base, 0);
    if (m) {
      const u32 p = base + (u32)__popcll(bal & ((1ull << lane) - 1ull));
      if (p < 128) smallkeys[p] = myk[i];
    }
  }
  __syncthreads();
  sort128(smallkeys, tid);
  const u64 T = smallkeys[rank_s];       // rank within candidate set
  __syncthreads();

  // gather the exactly-100 keys <= T (from registers)
  if (tid == 0) cnt_s = 0;
  if (tid < 128) smallkeys[tid] = ~0ull;
  __syncthreads();
  #pragma unroll
  for (int i = 0; i < 8; ++i) {
    const bool m = (myk[i] <= T);
    const u64 bal = __ballot(m);
    u32 base = 0;
    if (lane == 0 && bal) base = atomicAdd(&cnt_s, (u32)__popcll(bal));
    base = __shfl(base, 0);
    if (m) {
      const u32 p = base + (u32)__popcll(bal & ((1ull << lane) - 1ull));
      if (p < 128) smallkeys[p] = myk[i];
    }
  }
  __syncthreads();
  sort128(smallkeys, tid);

  if (tid < KK) {
    const u64 kv = smallkeys[tid];
    const float s = sortable_to_f32(~(u32)(kv >> 32));
    float x1 = 0.f, y1 = 0.f, x2 = 0.f, y2 = 0.f, so = 0.f, cf = -1.0f;
    if (s > -5.0e8f) {                     // valid = top_s > NEG*0.5
      const int c = (int)((kv >> 16) & 0xFFFFull);
      const int k = (int)(kv & 0xFFFFull);
      const float4 bx = cand_box[((size_t)b * CC + c) * KK + k];
      x1 = bx.x; y1 = bx.y; x2 = bx.z; y2 = bx.w;
      so = s; cf = (float)c;
    }
    float* o = out + ((size_t)b * KK + tid) * 6;
    o[0] = x1; o[1] = y1; o[2] = x2; o[3] = y2; o[4] = so; o[5] = cf;
  }
}

extern "C" void kernel_launch(void* const* d_in, const int* in_sizes, int n_in,
                              void* d_out, int out_size, void* d_ws, size_t ws_size,
                              hipStream_t stream) {
  (void)in_sizes; (void)n_in; (void)out_size; (void)ws_size;
  const float* rois   = (const float*)d_in[0];
  const float* scores = (const float*)d_in[1];
  const float* deltas = (const float*)d_in[2];
  const int*   im_hw  = (const int*)d_in[3];

  char* ws = (char*)d_ws;
  u64*    cand_key = (u64*)ws;                     // 4*80*100*8 = 256,000
  float4* cand_box = (float4*)(ws + 256000);       // 4*80*100*16= 512,000

  nms_fused<<<BB * CC, 512, 0, stream>>>(rois, scores, deltas, im_hw,
                                         cand_key, cand_box);
  topk_select<<<BB, 1024, 0, stream>>>(cand_key, cand_box, (float*)d_out);
}

// Round 19
// 55.670 us; speedup vs baseline: 1.1161x; 1.1161x over previous
//
#include <hip/hip_runtime.h>
#include <cstdint>

#define BB 4
#define RR 512
#define CC 80
#define KK 100
#define NMS_TH 0.3f
#define SCORE_TH 0.1f
#define DWH_CLIP 4.135166556742356f

typedef unsigned short u16;
typedef unsigned int u32;
typedef unsigned long long u64;

__device__ __forceinline__ u32 f32_sortable(float f) {
  u32 u = __float_as_uint(f);
  u32 mask = (u32)((int)u >> 31) | 0x80000000u;
  return u ^ mask;
}
__device__ __forceinline__ float sortable_to_f32(u32 s) {
  u32 u = (s & 0x80000000u) ? (s ^ 0x80000000u) : ~s;
  return __uint_as_float(u);
}

// Kernel 1 (R15 body + LDS aliasing = R17, best measured 55.78us): one block
// of 512 per (b,c). Fused: score-sort (LDS-hybrid bitonic, double-buffered in
// pool), decode, LAZY greedy NMS (ILP IoU loops, per-wave rmk slices,
// readlane scan chain). keyarr (8KB, dead after decode) overlaid with
// rmk_w/kbox/ksc/karea: static LDS ~18.5KB -> all 320 blocks co-resident.
// Certain-test (validated R4-R18): q > TH <=> inter*(1+TH)/TH > ai+aj+1e-9
// in reals; band +-2e-6 >> rounding error ~3e-7; exact IEEE-divide fallback.
__global__ __launch_bounds__(512) void nms_fused(
    const float* __restrict__ rois,     // [B,R,4]
    const float* __restrict__ scores,   // [B*R, C+1]
    const float* __restrict__ deltas,   // [B*R, (C+1)*4]
    const int*   __restrict__ im_hw,    // [B,2]
    u64*   __restrict__ cand_key,       // [B*C, K]
    float4* __restrict__ cand_box)      // [B*C, K]
{
#pragma clang fp contract(off)
  const int bc = blockIdx.x;
  const int b = bc / CC, c = bc % CC;
  const int tid = threadIdx.x;
  const int lane = tid & 63, wv = tid >> 6;

  __shared__ __align__(16) char pool[8192];  // keyarr | {rmk_w,kbox,ksc,karea}
  u64*    keyarr = (u64*)pool;               // [2*RR] during sort only
  u64*    rmk_w  = (u64*)pool;               // [8*64] after decode
  float4* kbox   = (float4*)(pool + 4096);   // [KK]
  float*  ksc    = (float*)(pool + 5696);    // [KK]
  float*  karea  = (float*)(pool + 6096);    // [KK]
  __shared__ float4 box_s[RR];               // 8 KB sorted boxes
  __shared__ float  sco_s[RR];               // 2 KB sorted scores
  __shared__ u64    supacc_arr[8];
  __shared__ int    nkept_s;

  const float fh = (float)im_hw[b * 2 + 0] - 1.0f;
  const float fw = (float)im_hw[b * 2 + 1] - 1.0f;

  // ---- hybrid bitonic sort: shfl for j<64, double-buffered LDS for j>=64 ----
  {
    const float sc = scores[(b * RR + tid) * (CC + 1) + (c + 1)];
    u64 v = ((u64)(~f32_sortable(sc)) << 32) | (u32)tid;  // score desc, idx asc
    const u32 t = (u32)tid;
    u32 pp = 0;
    for (u32 kk = 2; kk <= RR; kk <<= 1) {
      for (u32 j = kk >> 1; j > 0; j >>= 1) {
        u64 p;
        if (j >= 64) {
          u64* buf = keyarr + (pp & 1) * RR;
          buf[t] = v;
          __syncthreads();
          p = buf[t ^ j];
          ++pp;
        } else {
          p = __shfl_xor(v, (int)j);
        }
        bool up = ((t & kk) == 0);
        bool lower = ((t & j) == 0);
        bool takemin = (up == lower);
        bool pless = (p < v);
        v = (takemin == pless) ? p : v;
      }
    }
    __syncthreads();               // all lanes done reading buf before final write
    keyarr[t] = v;
  }
  __syncthreads();

  // ---- decode into sorted order ----
  {
    const u64 kv = keyarr[tid];
    const int r = (int)(kv & 0xFFFFFFFFull);
    const float sc = sortable_to_f32(~(u32)(kv >> 32));   // bit-exact original
    const float4 roi = *(const float4*)&rois[(b * RR + r) * 4];
    const int base = (b * RR + r) * (CC + 1) + (c + 1);
    const float4 d = *(const float4*)&deltas[base * 4];

    float w  = roi.z - roi.x;
    float h  = roi.w - roi.y;
    float cx = roi.x + 0.5f * w;
    float cy = roi.y + 0.5f * h;
    float dw = fminf(d.z, DWH_CLIP);
    float dh = fminf(d.w, DWH_CLIP);
    float pcx = d.x * w + cx;
    float pcy = d.y * h + cy;
    float pw = w * expf(dw);
    float ph = h * expf(dh);
    float hx = 0.5f * pw, hy = 0.5f * ph;
    float x1 = fminf(fmaxf(pcx - hx, 0.0f), fw);
    float y1 = fminf(fmaxf(pcy - hy, 0.0f), fh);
    float x2 = fminf(fmaxf(pcx + hx, 0.0f), fw);
    float y2 = fminf(fmaxf(pcy + hy, 0.0f), fh);

    box_s[tid] = make_float4(x1, y1, x2, y2);
    sco_s[tid] = sc;
    if (tid == 0) nkept_s = 0;
  }
  __syncthreads();                  // after this, keyarr is dead; aliases go live

  // ---- lazy greedy NMS over 8 chunks of 64 ----
  int nk = 0;
  for (int w = 0; w < 8 && nk < KK; ++w) {
    const float4 bxc = box_s[w * 64 + lane];
    const float ar = (bxc.z - bxc.x) * (bxc.w - bxc.y);
    const float areps = ar + 1e-9f;

    // (a) in-chunk row-mask slice: wave wv covers columns wv*8..wv*8+7.
    {
      float4 cb[8]; float ca[8]; float inA[8];
      #pragma unroll
      for (int jj = 0; jj < 8; ++jj) {
        cb[jj] = box_s[w * 64 + wv * 8 + jj];             // broadcast
        ca[jj] = (cb[jj].z - cb[jj].x) * (cb[jj].w - cb[jj].y);
      }
      u64 myrow = 0;
      u32 unca = 0;
      #pragma unroll
      for (int jj = 0; jj < 8; ++jj) {
        float iw = fminf(bxc.z, cb[jj].z) - fmaxf(bxc.x, cb[jj].x);
        float ih = fminf(bxc.w, cb[jj].w) - fmaxf(bxc.y, cb[jj].y);
        iw = fmaxf(iw, 0.0f);
        ih = fmaxf(ih, 0.0f);
        const float inter = iw * ih;
        inA[jj] = inter;
        const float S = ca[jj] + areps;
        const bool yes = inter * 4.3333247f > S;          // 13/3*(1-2e-6)
        const bool no  = inter * 4.3333420f < S;          // 13/3*(1+2e-6)
        myrow |= yes ? (1ull << jj) : 0ull;
        unca  |= (!(yes || no)) ? (1u << jj) : 0u;
      }
      if (__any(unca != 0)) {                             // ~never taken
        #pragma unroll
        for (int jj = 0; jj < 8; ++jj) {
          const float denom = ((ca[jj] + ar) - inA[jj]) + 1e-9f; // exact ref order
          const bool pe = inA[jj] / denom > NMS_TH;
          const u64 bit = 1ull << jj;
          if (unca & (1u << jj)) myrow = pe ? (myrow | bit) : (myrow & ~bit);
        }
      }
      myrow <<= (wv * 8);                                 // place at cols wv*8..+7
      myrow &= ~((2ull << lane) - 1ull);                  // only cols > row
      rmk_w[wv * 64 + lane] = myrow;
    }

    // (b) suppression by previously-kept, wave-strided; no per-iter __any
    {
      bool sup = false, unca = false;
      for (int kx = wv; kx < nk; kx += 8) {
        const float4 kb = kbox[kx];                       // broadcast
        const float ka = karea[kx];
        float iw = fminf(bxc.z, kb.z) - fmaxf(bxc.x, kb.x);
        float ih = fminf(bxc.w, kb.w) - fmaxf(bxc.y, kb.y);
        iw = fmaxf(iw, 0.0f);
        ih = fmaxf(ih, 0.0f);
        const float inter = iw * ih;
        const float S = ka + areps;
        const bool yes = inter * 4.3333247f > S;
        const bool no  = inter * 4.3333420f < S;
        sup  = sup  || yes;
        unca = unca || (!(yes || no));
      }
      if (__any(unca && !sup)) {                          // ~never taken
        sup = false;
        for (int kx = wv; kx < nk; kx += 8) {             // exact re-run
          const float4 kb = kbox[kx];
          const float ka = karea[kx];
          float iw = fminf(bxc.z, kb.z) - fmaxf(bxc.x, kb.x);
          float ih = fminf(bxc.w, kb.w) - fmaxf(bxc.y, kb.y);
          iw = fmaxf(iw, 0.0f);
          ih = fmaxf(ih, 0.0f);
          const float inter = iw * ih;
          const float denom = ((ka + ar) - inter) + 1e-9f; // exact ref order
          sup = sup || (inter / denom > NMS_TH);
        }
      }
      const u64 bal = __ballot(sup);
      if (lane == 0) supacc_arr[wv] = bal;
    }
    __syncthreads();

    // (c) serial scan (wave 0): scalar chain (ffs + readlane + and)
    if (wv == 0) {
      u64 sup2 = supacc_arr[0];
      #pragma unroll
      for (int ww = 1; ww < 8; ++ww) sup2 |= supacc_arr[ww];
      u64 rm = rmk_w[lane];
      #pragma unroll
      for (int ww = 1; ww < 8; ++ww) rm |= rmk_w[ww * 64 + lane];
      const u32 rlo = (u32)rm, rhi = (u32)(rm >> 32);
      u64 todo = __ballot(sco_s[w * 64 + lane] > SCORE_TH) & ~sup2;
      int nkl = nk;
      while (todo) {
        const int i = __ffsll((long long)todo) - 1;       // best remaining
        if (lane == 0) {
          const float4 kb = box_s[w * 64 + i];
          kbox[nkl] = kb;
          ksc[nkl] = sco_s[w * 64 + i];
          karea[nkl] = (kb.z - kb.x) * (kb.w - kb.y);
        }
        ++nkl;
        if (nkl >= KK) break;
        const u32 rl = (u32)__builtin_amdgcn_readlane((int)rlo, i);
        const u32 rh = (u32)__builtin_amdgcn_readlane((int)rhi, i);
        todo &= ~((2ull << i) - 1ull);                    // clear bits <= i
        todo &= ~(((u64)rh << 32) | rl);
      }
      if (lane == 0) nkept_s = nkl;
    }
    __syncthreads();
    nk = nkept_s;
  }

  // ---- emit candidates (pads unique, score = -1e9 = reference NEG) ----
  if (tid < KK) {
    const int kx = tid;
    u64 kv; float4 obx;
    if (kx < nk) {
      kv = ((u64)(~f32_sortable(ksc[kx])) << 32) | ((u64)(u32)c << 16) | (u32)kx;
      obx = kbox[kx];
    } else {
      kv = ((u64)(~f32_sortable(-1e9f)) << 32) | ((u64)(u32)c << 16) | (u32)kx;
      obx = make_float4(0.f, 0.f, 0.f, 0.f);
    }
    cand_key[bc * KK + kx] = kv;
    cand_box[bc * KK + kx] = obx;
  }
}

__device__ __forceinline__ void sort128(u64* smallkeys, int tid) {
  u64 v = (tid < 128) ? smallkeys[tid] : ~0ull;
  const u32 t = (u32)tid;
  for (u32 kk = 2; kk <= 128; kk <<= 1) {
    for (u32 j = kk >> 1; j > 0; j >>= 1) {
      if (j >= 64) {
        if (tid < 128) smallkeys[t] = v;
        __syncthreads();
        u64 p = (tid < 128) ? smallkeys[t ^ j] : ~0ull;
        __syncthreads();
        if (tid < 128) {
          bool up = ((t & kk) == 0);
          bool lower = ((t & j) == 0);
          bool takemin = (up == lower);
          bool pless = (p < v);
          v = (takemin == pless) ? p : v;
        }
      } else if (tid < 128) {
        u64 p = __shfl_xor(v, (int)j);
        bool up = ((t & kk) == 0);
        bool lower = ((t & j) == 0);
        bool takemin = (up == lower);
        bool pless = (p < v);
        v = (takemin == pless) ? p : v;
      }
    }
  }
  if (tid < 128) smallkeys[t] = v;
  __syncthreads();
}

// Kernel 2 (R15-proven): compaction-free register radix select per image.
__global__ __launch_bounds__(1024) void topk_select(
    const u64* __restrict__ cand_key,    // [B, C*K]
    const float4* __restrict__ cand_box, // [B*C, K]
    float* __restrict__ out)             // [B, K, 6]
{
  const int b = blockIdx.x;
  const int tid = threadIdx.x;
  const int lane = tid & 63, wv = tid >> 6;
  const int N = CC * KK;                 // 8000
  const u64* __restrict__ keys_g = cand_key + (size_t)b * N;

  __shared__ u32 whist[16][256];         // 16 KB
  __shared__ u32 bins[256];
  __shared__ u64 smallkeys[128];
  __shared__ int rank_s, q_s, ncand_s;
  __shared__ u32 cnt_s;

  u64 myk[8];
  #pragma unroll
  for (int i = 0; i < 8; ++i) {
    const int t = i * 1024 + tid;
    myk[i] = (t < N) ? keys_g[t] : ~0ull;
  }
  u32 mask8 = 0xFF;
  if (tid == 0) rank_s = KK - 1;

  int d = 7;
  int nc;
  for (;;) {
    for (int t = tid; t < 16 * 256; t += 1024) ((u32*)whist)[t] = 0;
    __syncthreads();
    const int sh = 8 * d;
    #pragma unroll
    for (int i = 0; i < 8; ++i) {
      if (mask8 & (1u << i)) {
        const u32 dig = (u32)((myk[i] >> sh) & 0xFF);
        atomicAdd(&whist[wv][dig], 1u);
      }
    }
    __syncthreads();
    if (tid < 256) {
      u32 s = 0;
      #pragma unroll
      for (int w = 0; w < 16; ++w) s += whist[w][tid];
      bins[tid] = s;
    }
    __syncthreads();
    if (wv == 0) {
      const u32 c0 = bins[lane * 4 + 0], c1 = bins[lane * 4 + 1];
      const u32 c2 = bins[lane * 4 + 2], c3 = bins[lane * 4 + 3];
      const u32 lsum = c0 + c1 + c2 + c3;
      u32 incl = lsum;
      #pragma unroll
      for (int off = 1; off < 64; off <<= 1) {
        const u32 v = __shfl_up(incl, off);
        if (lane >= off) incl += v;
      }
      const u32 excl = incl - lsum;
      const int rk = rank_s;
      const u32 s0 = excl, s1 = excl + c0, s2 = s1 + c1, s3 = s2 + c2;
      int q = -1; u32 nr = 0; u32 cnt = 0;
      if (rk >= (int)s0 && rk < (int)(s0 + c0)) { q = lane * 4 + 0; nr = rk - s0; cnt = c0; }
      else if (rk >= (int)s1 && rk < (int)(s1 + c1)) { q = lane * 4 + 1; nr = rk - s1; cnt = c1; }
      else if (rk >= (int)s2 && rk < (int)(s2 + c2)) { q = lane * 4 + 2; nr = rk - s2; cnt = c2; }
      else if (rk >= (int)s3 && rk < (int)(s3 + c3)) { q = lane * 4 + 3; nr = rk - s3; cnt = c3; }
      if (q >= 0) { q_s = q; rank_s = (int)nr; ncand_s = (int)cnt; }
    }
    __syncthreads();
    const u32 q = (u32)q_s;
    nc = ncand_s;
    #pragma unroll
    for (int i = 0; i < 8; ++i) {
      const u32 dig = (u32)((myk[i] >> sh) & 0xFF);
      if (dig != q) mask8 &= ~(1u << i);
    }
    if (nc <= 128 || d == 0) break;
    --d;
  }

  // gather the nc (<=128) candidates from registers
  if (tid == 0) cnt_s = 0;
  if (tid < 128) smallkeys[tid] = ~0ull;
  __syncthreads();
  #pragma unroll
  for (int i = 0; i < 8; ++i) {
    const bool m = (mask8 & (1u << i)) != 0;
    const u64 bal = __ballot(m);
    u32 base = 0;
    if (lane == 0 && bal) base = atomicAdd(&cnt_s, (u32)__popcll(bal));
    base = __shfl(base, 0);
    if (m) {
      const u32 p = base + (u32)__popcll(bal & ((1ull << lane) - 1ull));
      if (p < 128) smallkeys[p] = myk[i];
    }
  }
  __syncthreads();
  sort128(smallkeys, tid);
  const u64 T = smallkeys[rank_s];       // rank within candidate set
  __syncthreads();

  // gather the exactly-100 keys <= T (from registers)
  if (tid == 0) cnt_s = 0;
  if (tid < 128) smallkeys[tid] = ~0ull;
  __syncthreads();
  #pragma unroll
  for (int i = 0; i < 8; ++i) {
    const bool m = (myk[i] <= T);
    const u64 bal = __ballot(m);
    u32 base = 0;
    if (lane == 0 && bal) base = atomicAdd(&cnt_s, (u32)__popcll(bal));
    base = __shfl(base, 0);
    if (m) {
      const u32 p = base + (u32)__popcll(bal & ((1ull << lane) - 1ull));
      if (p < 128) smallkeys[p] = myk[i];
    }
  }
  __syncthreads();
  sort128(smallkeys, tid);

  if (tid < KK) {
    const u64 kv = smallkeys[tid];
    const float s = sortable_to_f32(~(u32)(kv >> 32));
    float x1 = 0.f, y1 = 0.f, x2 = 0.f, y2 = 0.f, so = 0.f, cf = -1.0f;
    if (s > -5.0e8f) {                     // valid = top_s > NEG*0.5
      const int c = (int)((kv >> 16) & 0xFFFFull);
      const int k = (int)(kv & 0xFFFFull);
      const float4 bx = cand_box[((size_t)b * CC + c) * KK + k];
      x1 = bx.x; y1 = bx.y; x2 = bx.z; y2 = bx.w;
      so = s; cf = (float)c;
    }
    float* o = out + ((size_t)b * KK + tid) * 6;
    o[0] = x1; o[1] = y1; o[2] = x2; o[3] = y2; o[4] = so; o[5] = cf;
  }
}

extern "C" void kernel_launch(void* const* d_in, const int* in_sizes, int n_in,
                              void* d_out, int out_size, void* d_ws, size_t ws_size,
                              hipStream_t stream) {
  (void)in_sizes; (void)n_in; (void)out_size; (void)ws_size;
  const float* rois   = (const float*)d_in[0];
  const float* scores = (const float*)d_in[1];
  const float* deltas = (const float*)d_in[2];
  const int*   im_hw  = (const int*)d_in[3];

  char* ws = (char*)d_ws;
  u64*    cand_key = (u64*)ws;                     // 4*80*100*8 = 256,000
  float4* cand_box = (float4*)(ws + 256000);       // 4*80*100*16= 512,000

  nms_fused<<<BB * CC, 512, 0, stream>>>(rois, scores, deltas, im_hw,
                                         cand_key, cand_box);
  topk_select<<<BB, 1024, 0, stream>>>(cand_key, cand_box, (float*)d_out);
}